// Round 1
// baseline (1663.954 us; speedup 1.0000x reference)
//
#include <hip/hip_runtime.h>
#include <hip/hip_bf16.h>
#include <cmath>

#define B_ 2
#define S_ 2048
#define H_ 4096
#define NH_ 16
#define HD_ 256
#define RD_ 64
#define F3_ 12288
#define TOK_ (B_*S_)

static constexpr float SCALE_ = 0.0625f; // 256^-0.5

typedef __bf16 bf16;
typedef bf16 bf16x8 __attribute__((ext_vector_type(8)));
typedef bf16 bf16x4 __attribute__((ext_vector_type(4)));
typedef float f32x4 __attribute__((ext_vector_type(4)));

union BU2 { unsigned int u; bf16 h[2]; };

// ---------- weight transpose + fp32->bf16 : out[N][K] = in[K][N] ----------
__global__ void k_tcvt(const float* __restrict__ in, bf16* __restrict__ out, int R, int C) {
  __shared__ float tile[32][33];
  int c0 = blockIdx.x * 32, r0 = blockIdx.y * 32;
  int x = threadIdx.x, y = threadIdx.y; // 32 x 8
#pragma unroll
  for (int k = 0; k < 4; ++k)
    tile[y + 8 * k][x] = in[(size_t)(r0 + y + 8 * k) * C + c0 + x];
  __syncthreads();
#pragma unroll
  for (int k = 0; k < 4; ++k)
    out[(size_t)(c0 + y + 8 * k) * R + r0 + x] = (bf16)tile[x][y + 8 * k];
}

// ---------- rope table ----------
__global__ void k_rope_table(float* __restrict__ cosT, float* __restrict__ sinT) {
  int pos = blockIdx.x, j = threadIdx.x; // 32 threads
  float invf = (float)pow(10000.0, -2.0 * (double)j / 64.0);
  float ang = (float)pos * invf;
  cosT[pos * 32 + j] = cosf(ang);
  sinT[pos * 32 + j] = sinf(ang);
}

// ---------- rope + reorder q,k -> (B,NH,S,HD) ----------
__global__ void k_rope_reorder(const bf16* __restrict__ qkv, const int* __restrict__ pid,
                               const float* __restrict__ cosT, const float* __restrict__ sinT,
                               bf16* __restrict__ Qo, bf16* __restrict__ Ko) {
  int tok = blockIdx.x;
  int b = tok >> 11, s = tok & (S_ - 1);
  int t = threadIdx.x;
  int hh = t >> 7, tt = t & 127;
  int pos = pid[tok];
  int d = tt * 2;
  float c = 1.f, sn = 0.f;
  if (tt < 32) { c = cosT[pos * 32 + tt]; sn = sinT[pos * 32 + tt]; }
#pragma unroll
  for (int hs = 0; hs < 8; ++hs) {
    int h = hs * 2 + hh;
    size_t iq = (size_t)tok * F3_ + h * HD_ + d;
    size_t oo = ((size_t)(b * NH_ + h) * S_ + s) * HD_ + d;
    BU2 q; q.u = *(const unsigned int*)(qkv + iq);
    BU2 k; k.u = *(const unsigned int*)(qkv + iq + 2 * H_); // k is the THIRD chunk (q,v,k split!)
    BU2 qo, ko;
    if (tt < 32) {
      float q1 = (float)q.h[0], q2 = (float)q.h[1];
      float k1 = (float)k.h[0], k2 = (float)k.h[1];
      qo.h[0] = (bf16)(q1 * c - q2 * sn); qo.h[1] = (bf16)(q2 * c + q1 * sn);
      ko.h[0] = (bf16)(k1 * c - k2 * sn); ko.h[1] = (bf16)(k2 * c + k1 * sn);
    } else { qo = q; ko = k; }
    *(unsigned int*)(Qo + oo) = qo.u;
    *(unsigned int*)(Ko + oo) = ko.u;
  }
}

// ---------- v -> V^T (B,NH,HD,S) ----------
__global__ void k_vtrans(const bf16* __restrict__ qkv, bf16* __restrict__ VT) {
  __shared__ float tile[64][129];
  int bid = blockIdx.x;
  int st = bid & 31, bh = bid >> 5;
  int b = bh >> 4, h = bh & 15;
  int t = threadIdx.x;
  for (int half = 0; half < 2; ++half) {
#pragma unroll
    for (int r = 0; r < 16; ++r) {
      int i = r * 4 + (t >> 6);
      int d = (t & 63) * 2;
      int s = st * 64 + i;
      size_t idx = (size_t)(b * S_ + s) * F3_ + H_ + h * HD_ + half * 128 + d; // v = second chunk
      BU2 v; v.u = *(const unsigned int*)(qkv + idx);
      tile[i][d] = (float)v.h[0];
      tile[i][d + 1] = (float)v.h[1];
    }
    __syncthreads();
    int i = t & 63, dg = t >> 6;
    size_t ob = ((size_t)bh * HD_ + half * 128) * S_ + st * 64 + i;
#pragma unroll
    for (int dd = 0; dd < 32; ++dd) {
      int dcol = dd * 4 + dg;
      VT[ob + (size_t)dcol * S_] = (bf16)tile[i][dcol];
    }
    __syncthreads();
  }
}

// ---------- GEMM: C[M][N] = A[M][K] * BT[N][K]^T ----------
template <bool A_F32, bool OUT_F32>
__global__ __launch_bounds__(256, 3)
void k_gemm(const void* __restrict__ Av, const bf16* __restrict__ BT,
            void* __restrict__ Cv, int Mm, int Nn, int Kk, int gx) {
  __shared__ bf16 As[2][128 * 40];
  __shared__ bf16 Bs[2][128 * 40];

  int nwg = gridDim.x;
  int bid = blockIdx.x;
  int cpx = nwg >> 3; // nwg % 8 == 0 in our launches
  int wg = (bid & 7) * cpx + (bid >> 3);
  int bx = wg % gx, by = wg / gx;
  int n0 = bx * 128, m0 = by * 128;

  int tid = threadIdx.x;
  int lane = tid & 63, wv = tid >> 6;
  int wr = wv >> 1, wc = wv & 1;

  const f32x4 Z4 = {0.f, 0.f, 0.f, 0.f};
  f32x4 acc[4][4];
#pragma unroll
  for (int i = 0; i < 4; ++i)
#pragma unroll
    for (int j = 0; j < 4; ++j) acc[i][j] = Z4;

  const int NT = Kk >> 5;

  float4 areg[4];
  bf16x8 areg16[2];
  bf16x8 breg[2];

  auto loadT = [&](int t) {
    int k0 = t * 32;
    if (A_F32) {
      const float* A = (const float*)Av;
#pragma unroll
      for (int r = 0; r < 4; ++r) {
        int row = r * 32 + (tid >> 3);
        areg[r] = *(const float4*)(A + (size_t)(m0 + row) * Kk + k0 + (tid & 7) * 4);
      }
    } else {
      const bf16* A = (const bf16*)Av;
#pragma unroll
      for (int r = 0; r < 2; ++r) {
        int row = r * 64 + (tid >> 2);
        areg16[r] = *(const bf16x8*)(A + (size_t)(m0 + row) * Kk + k0 + (tid & 3) * 8);
      }
    }
#pragma unroll
    for (int r = 0; r < 2; ++r) {
      int row = r * 64 + (tid >> 2);
      breg[r] = *(const bf16x8*)(BT + (size_t)(n0 + row) * Kk + k0 + (tid & 3) * 8);
    }
  };
  auto writeLds = [&](int buf) {
    if (A_F32) {
#pragma unroll
      for (int r = 0; r < 4; ++r) {
        int row = r * 32 + (tid >> 3);
        bf16x4 v;
        v[0] = (bf16)areg[r].x; v[1] = (bf16)areg[r].y;
        v[2] = (bf16)areg[r].z; v[3] = (bf16)areg[r].w;
        *(bf16x4*)&As[buf][row * 40 + (tid & 7) * 4] = v;
      }
    } else {
#pragma unroll
      for (int r = 0; r < 2; ++r) {
        int row = r * 64 + (tid >> 2);
        *(bf16x8*)&As[buf][row * 40 + (tid & 3) * 8] = areg16[r];
      }
    }
#pragma unroll
    for (int r = 0; r < 2; ++r) {
      int row = r * 64 + (tid >> 2);
      *(bf16x8*)&Bs[buf][row * 40 + (tid & 3) * 8] = breg[r];
    }
  };

  loadT(0);
  writeLds(0);
  __syncthreads();
  int cur = 0;
  for (int t = 0; t < NT; ++t) {
    if (t + 1 < NT) loadT(t + 1);
    bf16x8 af[4], bfr[4];
    int ko = (lane >> 4) * 8;
#pragma unroll
    for (int mt = 0; mt < 4; ++mt)
      af[mt] = *(const bf16x8*)&As[cur][(wr * 64 + mt * 16 + (lane & 15)) * 40 + ko];
#pragma unroll
    for (int nt = 0; nt < 4; ++nt)
      bfr[nt] = *(const bf16x8*)&Bs[cur][(wc * 64 + nt * 16 + (lane & 15)) * 40 + ko];
#pragma unroll
    for (int mt = 0; mt < 4; ++mt)
#pragma unroll
      for (int nt = 0; nt < 4; ++nt)
        acc[mt][nt] = __builtin_amdgcn_mfma_f32_16x16x32_bf16(af[mt], bfr[nt], acc[mt][nt], 0, 0, 0);
    if (t + 1 < NT) writeLds(cur ^ 1);
    __syncthreads();
    cur ^= 1;
  }

#pragma unroll
  for (int mt = 0; mt < 4; ++mt)
#pragma unroll
    for (int nt = 0; nt < 4; ++nt)
#pragma unroll
      for (int r = 0; r < 4; ++r) {
        int m = m0 + wr * 64 + mt * 16 + (lane >> 4) * 4 + r;
        int n = n0 + wc * 64 + nt * 16 + (lane & 15);
        if (OUT_F32)
          ((float*)Cv)[(size_t)m * Nn + n] = acc[mt][nt][r];
        else
          ((bf16*)Cv)[(size_t)m * Nn + n] = (bf16)acc[mt][nt][r];
      }
}

// ---------- flash attention (causal) ----------
__global__ __launch_bounds__(256, 2)
void k_attn(const bf16* __restrict__ Q, const bf16* __restrict__ K,
            const bf16* __restrict__ VT, bf16* __restrict__ O) {
  __shared__ bf16 Ks[64 * 256];
  __shared__ bf16 Vs[256 * 64];
  __shared__ bf16 Ps[4][16 * 80];

  int qt = blockIdx.x; // q tile (64 rows)
  int bh = blockIdx.y; // b*NH + h
  int tid = threadIdx.x;
  int lane = tid & 63, wv = tid >> 6;

  int qrow = qt * 64 + wv * 16 + (lane & 15);
  const bf16* Qb = Q + ((size_t)bh * S_ + qrow) * HD_;
  bf16x8 qf[8];
#pragma unroll
  for (int dc = 0; dc < 8; ++dc)
    qf[dc] = *(const bf16x8*)(Qb + dc * 32 + (lane >> 4) * 8);

  const f32x4 Z4 = {0.f, 0.f, 0.f, 0.f};
  f32x4 o[16];
#pragma unroll
  for (int i = 0; i < 16; ++i) o[i] = Z4;
  float m_i[4], l_i[4];
#pragma unroll
  for (int r = 0; r < 4; ++r) { m_i[r] = -INFINITY; l_i[r] = 0.f; }

  const bf16* Kb = K + (size_t)bh * S_ * HD_;
  const bf16* Vb = VT + (size_t)bh * HD_ * S_;

  for (int t = 0; t <= qt; ++t) {
    int kv0 = t * 64;
    // stage K tile [64][256], XOR-swizzled
    {
      int i0 = tid >> 5;
      int doff = (tid & 31) * 8;
#pragma unroll
      for (int it = 0; it < 8; ++it) {
        int row = it * 8 + i0;
        bf16x8 g = *(const bf16x8*)(Kb + (size_t)(kv0 + row) * HD_ + doff);
        int el = (row * 256 + doff) ^ ((row & 7) << 3);
        *(bf16x8*)&Ks[el] = g;
      }
      int d0 = tid >> 3;
      int koff = (tid & 7) * 8;
#pragma unroll
      for (int it = 0; it < 8; ++it) {
        int dr = it * 32 + d0;
        bf16x8 g = *(const bf16x8*)(Vb + (size_t)dr * S_ + kv0 + koff);
        int el = (dr * 64 + koff) ^ ((dr & 7) << 3);
        *(bf16x8*)&Vs[el] = g;
      }
    }
    __syncthreads();

    // QK^T
    f32x4 sa[4];
#pragma unroll
    for (int nt = 0; nt < 4; ++nt) sa[nt] = Z4;
#pragma unroll
    for (int dc = 0; dc < 8; ++dc)
#pragma unroll
      for (int nt = 0; nt < 4; ++nt) {
        int kvr = nt * 16 + (lane & 15);
        int el = (kvr * 256 + dc * 32 + (lane >> 4) * 8) ^ ((kvr & 7) << 3);
        sa[nt] = __builtin_amdgcn_mfma_f32_16x16x32_bf16(qf[dc], *(const bf16x8*)&Ks[el], sa[nt], 0, 0, 0);
      }

    // online softmax
    float p[4][4], mx[4];
    bool diag = (t == qt);
#pragma unroll
    for (int r = 0; r < 4; ++r) {
      float vmax = -INFINITY;
#pragma unroll
      for (int nt = 0; nt < 4; ++nt) {
        float v = sa[nt][r] * SCALE_;
        if (diag) {
          int q_abs = qt * 64 + wv * 16 + (lane >> 4) * 4 + r;
          int kv_abs = kv0 + nt * 16 + (lane & 15);
          if (kv_abs > q_abs) v = -1e30f;
        }
        p[nt][r] = v;
        vmax = fmaxf(vmax, v);
      }
      mx[r] = vmax;
    }
#pragma unroll
    for (int off = 1; off < 16; off <<= 1)
#pragma unroll
      for (int r = 0; r < 4; ++r) mx[r] = fmaxf(mx[r], __shfl_xor(mx[r], off));
    float sf[4], rs[4];
#pragma unroll
    for (int r = 0; r < 4; ++r) {
      float mnew = fmaxf(m_i[r], mx[r]);
      sf[r] = __expf(m_i[r] - mnew);
      float sum = 0.f;
#pragma unroll
      for (int nt = 0; nt < 4; ++nt) {
        p[nt][r] = __expf(p[nt][r] - mnew);
        sum += p[nt][r];
      }
      rs[r] = sum;
      m_i[r] = mnew;
    }
#pragma unroll
    for (int off = 1; off < 16; off <<= 1)
#pragma unroll
      for (int r = 0; r < 4; ++r) rs[r] += __shfl_xor(rs[r], off);
#pragma unroll
    for (int r = 0; r < 4; ++r) l_i[r] = l_i[r] * sf[r] + rs[r];
#pragma unroll
    for (int dt = 0; dt < 16; ++dt)
#pragma unroll
      for (int r = 0; r < 4; ++r) o[dt][r] *= sf[r];

    // P -> LDS (per-wave region, padded rows)
#pragma unroll
    for (int nt = 0; nt < 4; ++nt)
#pragma unroll
      for (int r = 0; r < 4; ++r)
        Ps[wv][((lane >> 4) * 4 + r) * 80 + nt * 16 + (lane & 15)] = (bf16)p[nt][r];

    // PV
#pragma unroll
    for (int kc = 0; kc < 2; ++kc) {
      bf16x8 pf = *(const bf16x8*)&Ps[wv][(lane & 15) * 80 + kc * 32 + (lane >> 4) * 8];
#pragma unroll
      for (int dt = 0; dt < 16; ++dt) {
        int drow = dt * 16 + (lane & 15);
        int el = (drow * 64 + kc * 32 + (lane >> 4) * 8) ^ ((drow & 7) << 3);
        o[dt] = __builtin_amdgcn_mfma_f32_16x16x32_bf16(pf, *(const bf16x8*)&Vs[el], o[dt], 0, 0, 0);
      }
    }
    __syncthreads();
  }

  int b = bh >> 4, h = bh & 15;
  float inv[4];
#pragma unroll
  for (int r = 0; r < 4; ++r) inv[r] = 1.0f / l_i[r];
#pragma unroll
  for (int dt = 0; dt < 16; ++dt)
#pragma unroll
    for (int r = 0; r < 4; ++r) {
      int q_abs = qt * 64 + wv * 16 + (lane >> 4) * 4 + r;
      O[((size_t)(b * S_ + q_abs)) * H_ + h * HD_ + dt * 16 + (lane & 15)] = (bf16)(o[dt][r] * inv[r]);
    }
}

extern "C" void kernel_launch(void* const* d_in, const int* in_sizes, int n_in,
                              void* d_out, int out_size, void* d_ws, size_t ws_size,
                              hipStream_t stream) {
  const float* hidden = (const float*)d_in[0];
  const int* pid = (const int*)d_in[1];
  const float* wqkv = (const float*)d_in[2];
  const float* wout = (const float*)d_in[3];
  float* outp = (float*)d_out;
  char* ws = (char*)d_ws;

  const size_t OFF_WQT = 0;
  const size_t OFF_WOT = OFF_WQT + (size_t)F3_ * H_ * 2;
  const size_t OFF_QKV = OFF_WOT + (size_t)H_ * H_ * 2;
  const size_t OFF_O = OFF_QKV; // alias: qkv fully consumed before O is written
  const size_t OFF_Q = OFF_QKV + (size_t)TOK_ * F3_ * 2;
  const size_t OFF_K = OFF_Q + (size_t)TOK_ * H_ * 2;
  const size_t OFF_VT = OFF_K + (size_t)TOK_ * H_ * 2;
  const size_t OFF_COS = OFF_VT + (size_t)TOK_ * H_ * 2;
  const size_t OFF_SIN = OFF_COS + (size_t)S_ * 32 * 4;
  const size_t TOTAL = OFF_SIN + (size_t)S_ * 32 * 4;
  if (ws_size < TOTAL) return;

  bf16* WqT = (bf16*)(ws + OFF_WQT);
  bf16* WoT = (bf16*)(ws + OFF_WOT);
  bf16* qkv = (bf16*)(ws + OFF_QKV);
  bf16* Obuf = (bf16*)(ws + OFF_O);
  bf16* Qb = (bf16*)(ws + OFF_Q);
  bf16* Kb = (bf16*)(ws + OFF_K);
  bf16* VTb = (bf16*)(ws + OFF_VT);
  float* cosT = (float*)(ws + OFF_COS);
  float* sinT = (float*)(ws + OFF_SIN);

  k_tcvt<<<dim3(F3_ / 32, H_ / 32), dim3(32, 8), 0, stream>>>(wqkv, WqT, H_, F3_);
  k_tcvt<<<dim3(H_ / 32, H_ / 32), dim3(32, 8), 0, stream>>>(wout, WoT, H_, H_);
  k_rope_table<<<dim3(S_), dim3(32), 0, stream>>>(cosT, sinT);
  k_gemm<true, false><<<dim3((F3_ / 128) * (TOK_ / 128)), dim3(256), 0, stream>>>(
      hidden, WqT, qkv, TOK_, F3_, H_, F3_ / 128);
  k_rope_reorder<<<dim3(TOK_), dim3(256), 0, stream>>>(qkv, pid, cosT, sinT, Qb, Kb);
  k_vtrans<<<dim3(B_ * NH_ * (S_ / 64)), dim3(256), 0, stream>>>(qkv, VTb);
  k_attn<<<dim3(S_ / 64, B_ * NH_), dim3(256), 0, stream>>>(Qb, Kb, VTb, Obuf);
  k_gemm<false, true><<<dim3((H_ / 128) * (TOK_ / 128)), dim3(256), 0, stream>>>(
      Obuf, WoT, outp, TOK_, H_, H_, H_ / 128);
}

// Round 5
// 1560.618 us; speedup vs baseline: 1.0662x; 1.0662x over previous
//
#include <hip/hip_runtime.h>
#include <hip/hip_bf16.h>
#include <cmath>

#define B_ 2
#define S_ 2048
#define H_ 4096
#define NH_ 16
#define HD_ 256
#define RD_ 64
#define F3_ 12288
#define TOK_ (B_*S_)

static constexpr float SCALE_ = 0.0625f; // 256^-0.5

typedef __bf16 bf16;
typedef bf16 bf16x8 __attribute__((ext_vector_type(8)));
typedef bf16 bf16x4 __attribute__((ext_vector_type(4)));
typedef float f32x4 __attribute__((ext_vector_type(4)));

union BU2 { unsigned int u; bf16 h[2]; };

// ---------- hidden fp32 -> bf16 ----------
__global__ void k_hcvt(const float* __restrict__ in, bf16* __restrict__ out, int n8) {
  int i = blockIdx.x * 256 + threadIdx.x;
  if (i >= n8) return;
  const float4* p = (const float4*)in + (size_t)i * 2;
  float4 a = p[0], b = p[1];
  bf16x8 v;
  v[0] = (bf16)a.x; v[1] = (bf16)a.y; v[2] = (bf16)a.z; v[3] = (bf16)a.w;
  v[4] = (bf16)b.x; v[5] = (bf16)b.y; v[6] = (bf16)b.z; v[7] = (bf16)b.w;
  ((bf16x8*)out)[i] = v;
}

// ---------- weight transpose + fp32->bf16 : out[N][K] = in[K][N] ----------
__global__ void k_tcvt(const float* __restrict__ in, bf16* __restrict__ out, int R, int C) {
  __shared__ float tile[32][33];
  int c0 = blockIdx.x * 32, r0 = blockIdx.y * 32;
  int x = threadIdx.x, y = threadIdx.y; // 32 x 8
#pragma unroll
  for (int k = 0; k < 4; ++k)
    tile[y + 8 * k][x] = in[(size_t)(r0 + y + 8 * k) * C + c0 + x];
  __syncthreads();
#pragma unroll
  for (int k = 0; k < 4; ++k)
    out[(size_t)(c0 + y + 8 * k) * R + r0 + x] = (bf16)tile[x][y + 8 * k];
}

// ---------- rope table ----------
__global__ void k_rope_table(float* __restrict__ cosT, float* __restrict__ sinT) {
  int pos = blockIdx.x, j = threadIdx.x; // 32 threads
  float invf = (float)pow(10000.0, -2.0 * (double)j / 64.0);
  float ang = (float)pos * invf;
  cosT[pos * 32 + j] = cosf(ang);
  sinT[pos * 32 + j] = sinf(ang);
}

// ---------- rope + reorder q,k -> (B,NH,S,HD) ----------
__global__ void k_rope_reorder(const bf16* __restrict__ qkv, const int* __restrict__ pid,
                               const float* __restrict__ cosT, const float* __restrict__ sinT,
                               bf16* __restrict__ Qo, bf16* __restrict__ Ko) {
  int tok = blockIdx.x;
  int b = tok >> 11, s = tok & (S_ - 1);
  int t = threadIdx.x;
  int hh = t >> 7, tt = t & 127;
  int pos = pid[tok];
  int d = tt * 2;
  float c = 1.f, sn = 0.f;
  if (tt < 32) { c = cosT[pos * 32 + tt]; sn = sinT[pos * 32 + tt]; }
#pragma unroll
  for (int hs = 0; hs < 8; ++hs) {
    int h = hs * 2 + hh;
    size_t iq = (size_t)tok * F3_ + h * HD_ + d;
    size_t oo = ((size_t)(b * NH_ + h) * S_ + s) * HD_ + d;
    BU2 q; q.u = *(const unsigned int*)(qkv + iq);
    BU2 k; k.u = *(const unsigned int*)(qkv + iq + 2 * H_); // k is the THIRD chunk (q,v,k split!)
    BU2 qo, ko;
    if (tt < 32) {
      float q1 = (float)q.h[0], q2 = (float)q.h[1];
      float k1 = (float)k.h[0], k2 = (float)k.h[1];
      qo.h[0] = (bf16)(q1 * c - q2 * sn); qo.h[1] = (bf16)(q2 * c + q1 * sn);
      ko.h[0] = (bf16)(k1 * c - k2 * sn); ko.h[1] = (bf16)(k2 * c + k1 * sn);
    } else { qo = q; ko = k; }
    *(unsigned int*)(Qo + oo) = qo.u;
    *(unsigned int*)(Ko + oo) = ko.u;
  }
}

// ---------- v -> V^T (B,NH,HD,S) ----------
__global__ void k_vtrans(const bf16* __restrict__ qkv, bf16* __restrict__ VT) {
  __shared__ float tile[64][129];
  int bid = blockIdx.x;
  int st = bid & 31, bh = bid >> 5;
  int b = bh >> 4, h = bh & 15;
  int t = threadIdx.x;
  for (int half = 0; half < 2; ++half) {
#pragma unroll
    for (int r = 0; r < 16; ++r) {
      int i = r * 4 + (t >> 6);
      int d = (t & 63) * 2;
      int s = st * 64 + i;
      size_t idx = (size_t)(b * S_ + s) * F3_ + H_ + h * HD_ + half * 128 + d; // v = second chunk
      BU2 v; v.u = *(const unsigned int*)(qkv + idx);
      tile[i][d] = (float)v.h[0];
      tile[i][d + 1] = (float)v.h[1];
    }
    __syncthreads();
    int i = t & 63, dg = t >> 6;
    size_t ob = ((size_t)bh * HD_ + half * 128) * S_ + st * 64 + i;
#pragma unroll
    for (int dd = 0; dd < 32; ++dd) {
      int dcol = dd * 4 + dg;
      VT[ob + (size_t)dcol * S_] = (bf16)tile[i][dcol];
    }
    __syncthreads();
  }
}

// ===================== 256x256 8-phase GEMM =====================
// C[M][N] = A[M][K] * BT[N][K]^T, K=4096, bf16 in, fp32 acc.
// 512 thr (8 waves, 2Mx4N), BK=64, LDS 128KB (A/B x dbuf, 32KB each),
// st_16x32 swizzle (byte ^= ((byte>>9)&1)<<5) via inverse-swizzled
// global_load_lds source + swizzled ds_read. Counted vmcnt(4) @ phases 4/8.
// Stage schedule (iter j; T1=2j+1,T2=2j+2,T3=2j+3):
//  p1:T1.Ah0->As1  p2:T1.Ah1->As1  p3:T2.Bh0->Bs0  p4:T2.Bh1->Bs0 [vm4]
//  p5:T2.Ah0->As0  p6:T2.Ah1->As0  p7:T3.Bh0->Bs1  p8:T3.Bh1->Bs1 [vm4]
// Reads: p1 A(mh0)+B(nh0); p2 B(nh1); p3 A(mh1); p4 none. Every slot is
// re-staged >=1 barrier after its last read, lands >=2 phases before reuse.
// R4 BUGFIX: source row must include half*128 (was duplicating rows 0-127
// into both LDS halves -> absmax 0.18).

#define GK_ 4096

#define STG(dst, half, src, row0, k0)                                                     \
  do {                                                                                    \
    const bf16* _s0 = (src) + (size_t)((row0) + (half) * 128 + sr0) * GK_ + (k0) + sc0;   \
    const bf16* _s1 = (src) + (size_t)((row0) + (half) * 128 + sr1) * GK_ + (k0) + sc1;   \
    __builtin_amdgcn_global_load_lds(                                                     \
        (const __attribute__((address_space(1))) void*)_s0,                               \
        (__attribute__((address_space(3))) void*)((char*)(dst) + (half) * 16384 + so0),   \
        16, 0, 0);                                                                        \
    __builtin_amdgcn_global_load_lds(                                                     \
        (const __attribute__((address_space(1))) void*)_s1,                               \
        (__attribute__((address_space(3))) void*)((char*)(dst) + (half) * 16384 + so1),   \
        16, 0, 0);                                                                        \
  } while (0)

#define LDA(buf, mh)                                                                      \
  _Pragma("unroll") for (int mt = 0; mt < 4; ++mt)                                        \
  _Pragma("unroll") for (int kk = 0; kk < 2; ++kk)                                        \
    aF[mt][kk] = *(const bf16x8*)((const char*)(buf) + aBase + ((mh)*4 + mt) * 2048 + kk * 64);

#define LDB(dst, buf, nh)                                                                 \
  _Pragma("unroll") for (int nt = 0; nt < 2; ++nt)                                        \
  _Pragma("unroll") for (int kk = 0; kk < 2; ++kk)                                        \
    dst[nt][kk] = *(const bf16x8*)((const char*)(buf) + bBase + ((nh)*2 + nt) * 2048 + kk * 64);

#define MM(mh, nh, bfrag)                                                                 \
  _Pragma("unroll") for (int mt = 0; mt < 4; ++mt)                                        \
  _Pragma("unroll") for (int nt = 0; nt < 2; ++nt)                                        \
  _Pragma("unroll") for (int kk = 0; kk < 2; ++kk)                                        \
    acc[(mh)*4 + mt][(nh)*2 + nt] = __builtin_amdgcn_mfma_f32_16x16x32_bf16(              \
        aF[mt][kk], bfrag[nt][kk], acc[(mh)*4 + mt][(nh)*2 + nt], 0, 0, 0);

#define BAR __builtin_amdgcn_s_barrier()
#define LGKM0 asm volatile("s_waitcnt lgkmcnt(0)" ::: "memory")
#define VMW4 asm volatile("s_waitcnt vmcnt(4)" ::: "memory")
#define VMW0 asm volatile("s_waitcnt vmcnt(0)" ::: "memory")
#define PRIO1 __builtin_amdgcn_s_setprio(1)
#define PRIO0 __builtin_amdgcn_s_setprio(0)

template <bool OUT_F32>
__global__ __launch_bounds__(512, 1)
void k_gemm8(const bf16* __restrict__ A, const bf16* __restrict__ BT,
             void* __restrict__ Cv, int Nn, int gx) {
  __shared__ bf16 As0[256 * 64];
  __shared__ bf16 As1[256 * 64];
  __shared__ bf16 Bs0[256 * 64];
  __shared__ bf16 Bs1[256 * 64];

  // bijective XCD swizzle (m204)
  int nwg = gridDim.x;
  int bid = blockIdx.x;
  int q = nwg >> 3, r = nwg & 7;
  int xcd = bid & 7, lid = bid >> 3;
  int wg = (xcd < r ? xcd * (q + 1) : r * (q + 1) + (xcd - r) * q) + lid;
  int bx = wg % gx, by = wg / gx;
  int m0 = by * 256, n0 = bx * 256;

  int tid = threadIdx.x;
  int lane = tid & 63, w = tid >> 6;
  int wr = w >> 2, wc = w & 3;
  int lrow = lane & 15, g = lane >> 4;
  int sig = (lrow >> 2) & 1;
  int cswz = (g * 16) ^ (sig << 5);
  int aBase = (wr * 128 + lrow) * 128 + cswz;  // byte offset in A buffer
  int bBase = (wc * 64 + lrow) * 128 + cswz;   // byte offset in B buffer

  // staging: 2 chunks/thread per half-tile (128 rows x 64 cols)
  int ci0 = w * 64 + lane;
  int ci1 = 512 + ci0;
  int sr0 = ci0 >> 3, sr1 = ci1 >> 3;
  int sc0 = ((ci0 & 7) ^ (((ci0 >> 5) & 1) << 1)) * 8;
  int sc1 = ((ci1 & 7) ^ (((ci1 >> 5) & 1) << 1)) * 8;
  int so0 = ci0 * 16, so1 = ci1 * 16;

  // prologue: T0 all 4 halves + T1.Bh0/Bh1
  STG(As0, 0, A, m0, 0);
  STG(As0, 1, A, m0, 0);
  STG(Bs0, 0, BT, n0, 0);
  STG(Bs0, 1, BT, n0, 0);
  STG(Bs1, 0, BT, n0, 64);
  STG(Bs1, 1, BT, n0, 64);

  const f32x4 Z4 = {0.f, 0.f, 0.f, 0.f};
  f32x4 acc[8][4];
#pragma unroll
  for (int i = 0; i < 8; ++i)
#pragma unroll
    for (int jj = 0; jj < 4; ++jj) acc[i][jj] = Z4;

  bf16x8 aF[4][2], bFa[2][2], bFb[2][2];

  VMW4;
  BAR;

  const int NIT = GK_ / 128; // 2 K-tiles of 64 per iteration
  for (int j = 0; j < NIT; ++j) {
    bool last = (j == NIT - 1);
    int kT1 = (2 * j + 1) * 64;
    int kT2 = (2 * j + 2) * 64;
    int kT3 = (2 * j + 3) * 64;
    // phase 1: reads A(mh0)+B(nh0) of buf0 | stage T1.Ah0
    LDA(As0, 0); LDB(bFa, Bs0, 0);
    STG(As1, 0, A, m0, kT1);
    BAR; LGKM0; PRIO1; MM(0, 0, bFa); PRIO0; BAR;
    // phase 2: reads B(nh1) | stage T1.Ah1
    LDB(bFb, Bs0, 1);
    STG(As1, 1, A, m0, kT1);
    BAR; LGKM0; PRIO1; MM(0, 1, bFb); PRIO0; BAR;
    // phase 3: reads A(mh1) | stage T2.Bh0
    LDA(As0, 1);
    if (!last) STG(Bs0, 0, BT, n0, kT2);
    BAR; LGKM0; PRIO1; MM(1, 1, bFb); PRIO0; BAR;
    // phase 4: no reads | stage T2.Bh1 | counted vmcnt
    if (!last) { STG(Bs0, 1, BT, n0, kT2); VMW4; } else { VMW0; }
    BAR; PRIO1; MM(1, 0, bFa); PRIO0; BAR;
    // phase 5: buf1 reads A(mh0)+B(nh0) | stage T2.Ah0
    LDA(As1, 0); LDB(bFa, Bs1, 0);
    if (!last) STG(As0, 0, A, m0, kT2);
    BAR; LGKM0; PRIO1; MM(0, 0, bFa); PRIO0; BAR;
    // phase 6: reads B(nh1) | stage T2.Ah1
    LDB(bFb, Bs1, 1);
    if (!last) STG(As0, 1, A, m0, kT2);
    BAR; LGKM0; PRIO1; MM(0, 1, bFb); PRIO0; BAR;
    // phase 7: reads A(mh1) | stage T3.Bh0
    LDA(As1, 1);
    if (!last) STG(Bs1, 0, BT, n0, kT3);
    BAR; LGKM0; PRIO1; MM(1, 1, bFb); PRIO0; BAR;
    // phase 8: no reads | stage T3.Bh1 | counted vmcnt
    if (!last) { STG(Bs1, 1, BT, n0, kT3); VMW4; }
    BAR; PRIO1; MM(1, 0, bFa); PRIO0; BAR;
  }

  // epilogue C-write
#pragma unroll
  for (int mt = 0; mt < 8; ++mt)
#pragma unroll
    for (int nt = 0; nt < 4; ++nt)
#pragma unroll
      for (int rr = 0; rr < 4; ++rr) {
        int m = m0 + wr * 128 + mt * 16 + g * 4 + rr;
        int n = n0 + wc * 64 + nt * 16 + lrow;
        if (OUT_F32)
          ((float*)Cv)[(size_t)m * Nn + n] = acc[mt][nt][rr];
        else
          ((bf16*)Cv)[(size_t)m * Nn + n] = (bf16)acc[mt][nt][rr];
      }
}

// ---------- flash attention (causal) ----------
__global__ __launch_bounds__(256, 2)
void k_attn(const bf16* __restrict__ Q, const bf16* __restrict__ K,
            const bf16* __restrict__ VT, bf16* __restrict__ O) {
  __shared__ bf16 Ks[64 * 256];
  __shared__ bf16 Vs[256 * 64];
  __shared__ bf16 Ps[4][16 * 80];

  int qt = blockIdx.x; // q tile (64 rows)
  int bh = blockIdx.y; // b*NH + h
  int tid = threadIdx.x;
  int lane = tid & 63, wv = tid >> 6;

  int qrow = qt * 64 + wv * 16 + (lane & 15);
  const bf16* Qb = Q + ((size_t)bh * S_ + qrow) * HD_;
  bf16x8 qf[8];
#pragma unroll
  for (int dc = 0; dc < 8; ++dc)
    qf[dc] = *(const bf16x8*)(Qb + dc * 32 + (lane >> 4) * 8);

  const f32x4 Z4 = {0.f, 0.f, 0.f, 0.f};
  f32x4 o[16];
#pragma unroll
  for (int i = 0; i < 16; ++i) o[i] = Z4;
  float m_i[4], l_i[4];
#pragma unroll
  for (int r = 0; r < 4; ++r) { m_i[r] = -INFINITY; l_i[r] = 0.f; }

  const bf16* Kb = K + (size_t)bh * S_ * HD_;
  const bf16* Vb = VT + (size_t)bh * HD_ * S_;

  for (int t = 0; t <= qt; ++t) {
    int kv0 = t * 64;
    {
      int i0 = tid >> 5;
      int doff = (tid & 31) * 8;
#pragma unroll
      for (int it = 0; it < 8; ++it) {
        int row = it * 8 + i0;
        bf16x8 gld = *(const bf16x8*)(Kb + (size_t)(kv0 + row) * HD_ + doff);
        int el = (row * 256 + doff) ^ ((row & 7) << 3);
        *(bf16x8*)&Ks[el] = gld;
      }
      int d0 = tid >> 3;
      int koff = (tid & 7) * 8;
#pragma unroll
      for (int it = 0; it < 8; ++it) {
        int dr = it * 32 + d0;
        bf16x8 gld = *(const bf16x8*)(Vb + (size_t)dr * S_ + kv0 + koff);
        int el = (dr * 64 + koff) ^ ((dr & 7) << 3);
        *(bf16x8*)&Vs[el] = gld;
      }
    }
    __syncthreads();

    f32x4 sa[4];
#pragma unroll
    for (int nt = 0; nt < 4; ++nt) sa[nt] = Z4;
#pragma unroll
    for (int dc = 0; dc < 8; ++dc)
#pragma unroll
      for (int nt = 0; nt < 4; ++nt) {
        int kvr = nt * 16 + (lane & 15);
        int el = (kvr * 256 + dc * 32 + (lane >> 4) * 8) ^ ((kvr & 7) << 3);
        sa[nt] = __builtin_amdgcn_mfma_f32_16x16x32_bf16(qf[dc], *(const bf16x8*)&Ks[el], sa[nt], 0, 0, 0);
      }

    float p[4][4], mx[4];
    bool diag = (t == qt);
#pragma unroll
    for (int r = 0; r < 4; ++r) {
      float vmax = -INFINITY;
#pragma unroll
      for (int nt = 0; nt < 4; ++nt) {
        float v = sa[nt][r] * SCALE_;
        if (diag) {
          int q_abs = qt * 64 + wv * 16 + (lane >> 4) * 4 + r;
          int kv_abs = kv0 + nt * 16 + (lane & 15);
          if (kv_abs > q_abs) v = -1e30f;
        }
        p[nt][r] = v;
        vmax = fmaxf(vmax, v);
      }
      mx[r] = vmax;
    }
#pragma unroll
    for (int off = 1; off < 16; off <<= 1)
#pragma unroll
      for (int r = 0; r < 4; ++r) mx[r] = fmaxf(mx[r], __shfl_xor(mx[r], off));
    float sf[4], rs[4];
#pragma unroll
    for (int r = 0; r < 4; ++r) {
      float mnew = fmaxf(m_i[r], mx[r]);
      sf[r] = __expf(m_i[r] - mnew);
      float sum = 0.f;
#pragma unroll
      for (int nt = 0; nt < 4; ++nt) {
        p[nt][r] = __expf(p[nt][r] - mnew);
        sum += p[nt][r];
      }
      rs[r] = sum;
      m_i[r] = mnew;
    }
#pragma unroll
    for (int off = 1; off < 16; off <<= 1)
#pragma unroll
      for (int r = 0; r < 4; ++r) rs[r] += __shfl_xor(rs[r], off);
#pragma unroll
    for (int r = 0; r < 4; ++r) l_i[r] = l_i[r] * sf[r] + rs[r];
#pragma unroll
    for (int dt = 0; dt < 16; ++dt)
#pragma unroll
      for (int r = 0; r < 4; ++r) o[dt][r] *= sf[r];

#pragma unroll
    for (int nt = 0; nt < 4; ++nt)
#pragma unroll
      for (int r = 0; r < 4; ++r)
        Ps[wv][((lane >> 4) * 4 + r) * 80 + nt * 16 + (lane & 15)] = (bf16)p[nt][r];

#pragma unroll
    for (int kc = 0; kc < 2; ++kc) {
      bf16x8 pf = *(const bf16x8*)&Ps[wv][(lane & 15) * 80 + kc * 32 + (lane >> 4) * 8];
#pragma unroll
      for (int dt = 0; dt < 16; ++dt) {
        int drow = dt * 16 + (lane & 15);
        int el = (drow * 64 + kc * 32 + (lane >> 4) * 8) ^ ((drow & 7) << 3);
        o[dt] = __builtin_amdgcn_mfma_f32_16x16x32_bf16(pf, *(const bf16x8*)&Vs[el], o[dt], 0, 0, 0);
      }
    }
    __syncthreads();
  }

  int b = bh >> 4, h = bh & 15;
  float inv[4];
#pragma unroll
  for (int r = 0; r < 4; ++r) inv[r] = 1.0f / l_i[r];
#pragma unroll
  for (int dt = 0; dt < 16; ++dt)
#pragma unroll
    for (int r = 0; r < 4; ++r) {
      int q_abs = qt * 64 + wv * 16 + (lane >> 4) * 4 + r;
      O[((size_t)(b * S_ + q_abs)) * H_ + h * HD_ + dt * 16 + (lane & 15)] = (bf16)(o[dt][r] * inv[r]);
    }
}

extern "C" void kernel_launch(void* const* d_in, const int* in_sizes, int n_in,
                              void* d_out, int out_size, void* d_ws, size_t ws_size,
                              hipStream_t stream) {
  const float* hidden = (const float*)d_in[0];
  const int* pid = (const int*)d_in[1];
  const float* wqkv = (const float*)d_in[2];
  const float* wout = (const float*)d_in[3];
  float* outp = (float*)d_out;
  char* ws = (char*)d_ws;

  const size_t OFF_WQT = 0;
  const size_t OFF_WOT = OFF_WQT + (size_t)F3_ * H_ * 2;
  const size_t OFF_QKV = OFF_WOT + (size_t)H_ * H_ * 2;
  const size_t OFF_O = OFF_QKV; // alias: qkv fully consumed before O is written
  const size_t OFF_Q = OFF_QKV + (size_t)TOK_ * F3_ * 2;
  const size_t OFF_K = OFF_Q + (size_t)TOK_ * H_ * 2;
  const size_t OFF_VT = OFF_K + (size_t)TOK_ * H_ * 2;
  const size_t OFF_COS = OFF_VT + (size_t)TOK_ * H_ * 2;
  const size_t OFF_SIN = OFF_COS + (size_t)S_ * 32 * 4;
  const size_t TOTAL = OFF_SIN + (size_t)S_ * 32 * 4;
  if (ws_size < TOTAL) return;

  bf16* WqT = (bf16*)(ws + OFF_WQT);
  bf16* WoT = (bf16*)(ws + OFF_WOT);
  bf16* qkv = (bf16*)(ws + OFF_QKV);
  bf16* Obuf = (bf16*)(ws + OFF_O);
  bf16* Qb = (bf16*)(ws + OFF_Q);
  bf16* Kb = (bf16*)(ws + OFF_K);
  bf16* VTb = (bf16*)(ws + OFF_VT);
  float* cosT = (float*)(ws + OFF_COS);
  float* sinT = (float*)(ws + OFF_SIN);
  bf16* HB = (bf16*)(ws + OFF_Q); // hidden-bf16 aliases Q region (free until rope_reorder)

  k_tcvt<<<dim3(F3_ / 32, H_ / 32), dim3(32, 8), 0, stream>>>(wqkv, WqT, H_, F3_);
  k_tcvt<<<dim3(H_ / 32, H_ / 32), dim3(32, 8), 0, stream>>>(wout, WoT, H_, H_);
  k_rope_table<<<dim3(S_), dim3(32), 0, stream>>>(cosT, sinT);
  k_hcvt<<<dim3(TOK_ * H_ / 8 / 256), dim3(256), 0, stream>>>(hidden, HB, TOK_ * H_ / 8);
  k_gemm8<false><<<dim3((F3_ / 256) * (TOK_ / 256)), dim3(512), 0, stream>>>(
      HB, WqT, qkv, F3_, F3_ / 256);
  k_rope_reorder<<<dim3(TOK_), dim3(256), 0, stream>>>(qkv, pid, cosT, sinT, Qb, Kb);
  k_vtrans<<<dim3(B_ * NH_ * (S_ / 64)), dim3(256), 0, stream>>>(qkv, VTb);
  k_attn<<<dim3(S_ / 64, B_ * NH_), dim3(256), 0, stream>>>(Qb, Kb, VTb, Obuf);
  k_gemm8<true><<<dim3((H_ / 256) * (TOK_ / 256)), dim3(512), 0, stream>>>(
      Obuf, WoT, outp, H_, H_ / 256);
}